// Round 2
// baseline (4032.508 us; speedup 1.0000x reference)
//
#include <hip/hip_runtime.h>
#include <hip/hip_bf16.h>
#include <cstddef>

typedef __hip_bfloat16 bf16;

static constexpr int BATCH = 16;
static constexpr int CH    = 512;    // DIM
static constexpr int NPOS  = 4096;   // h*w
static constexpr int OQKV  = 1536;   // 3*HID
static constexpr int NHEAD = 8;
static constexpr int DHEAD = 64;
#define EPSF 1e-5f
#define QSCALE 0.125f   // DIM_HEAD^-0.5

__device__ __forceinline__ float b2f(bf16 v){ return __bfloat162float(v); }
__device__ __forceinline__ bf16  f2b(float v){ return __float2bfloat16(v); }
__device__ __forceinline__ float ldv(const float* p, size_t i){ return p[i]; }
__device__ __forceinline__ float ldv(const bf16*  p, size_t i){ return __bfloat162float(p[i]); }

// ---------------- K1: channel-LN stats per (b,p), fp32 input ----------------
__global__ __launch_bounds__(256) void ln_stats_kernel(
    const float* __restrict__ x, float* __restrict__ mean, float* __restrict__ rstd)
{
    int g = blockIdx.x * 256 + threadIdx.x;   // 0..65535
    int b = g >> 12, p = g & 4095;
    const float* xp = x + (size_t)b * CH * NPOS + p;
    float s = 0.f, s2 = 0.f;
    for (int c = 0; c < CH; c++) {
        float v = xp[(size_t)c * NPOS];
        s += v; s2 += v * v;
    }
    float m = s * (1.f / CH);
    float var = s2 * (1.f / CH) - m * m;
    mean[g] = m;
    rstd[g] = rsqrtf(var + EPSF);
}

// ---------------- K2/K7: channel GEMM (64x64 tile, 256 thr, 4x4 micro) ----
// out[b, outChanOff+o, p] = sum_c W[o*512+c] * Xval(b, xChanOff+c, p) (+bias[o])
// Xval = (mean!=null) ? (x-mean[p])*rstd[p]*g[c] : raw
template <typename TX>
__global__ __launch_bounds__(256) void gemm_chan_kernel(
    const float* __restrict__ W, const TX* __restrict__ X,
    const float* __restrict__ mean, const float* __restrict__ rstd,
    const float* __restrict__ g, const float* __restrict__ bias,
    bf16* __restrict__ out,
    int xChanTot, int xChanOff, int outChanTot, int outChanOff)
{
    __shared__ float Wt[32][65];   // [c][o]
    __shared__ float Xt[32][65];   // [c][p]
    int tid = threadIdx.x;
    int tx = tid & 15, ty = tid >> 4;
    int pT = blockIdx.x * 64;
    int oT = blockIdx.y * 64;
    int b  = blockIdx.z;
    const TX* Xb = X + ((size_t)b * xChanTot + xChanOff) * NPOS;
    const float* mb = mean ? mean + (size_t)b * NPOS : nullptr;
    const float* rb = rstd ? rstd + (size_t)b * NPOS : nullptr;
    float acc[4][4] = {};
    for (int cT = 0; cT < CH; cT += 32) {
        for (int l = tid; l < 64 * 32; l += 256) {
            int r = l >> 5, cc = l & 31;          // r: o-row, cc: c-col
            Wt[cc][r] = W[(size_t)(oT + r) * CH + cT + cc];
        }
        for (int l = tid; l < 32 * 64; l += 256) {
            int r = l >> 6, pp = l & 63;          // r: c-row, pp: p-col
            float v = ldv(Xb, (size_t)(cT + r) * NPOS + pT + pp);
            if (mb) v = (v - mb[pT + pp]) * rb[pT + pp] * g[cT + r];
            Xt[r][pp] = v;
        }
        __syncthreads();
        #pragma unroll
        for (int kk = 0; kk < 32; kk++) {
            float a[4], bb[4];
            #pragma unroll
            for (int i = 0; i < 4; i++) a[i]  = Wt[kk][ty * 4 + i];
            #pragma unroll
            for (int j = 0; j < 4; j++) bb[j] = Xt[kk][tx * 4 + j];
            #pragma unroll
            for (int i = 0; i < 4; i++)
                #pragma unroll
                for (int j = 0; j < 4; j++) acc[i][j] += a[i] * bb[j];
        }
        __syncthreads();
    }
    bf16* ob = out + ((size_t)b * outChanTot + outChanOff) * NPOS;
    #pragma unroll
    for (int i = 0; i < 4; i++) {
        int o = oT + ty * 4 + i;
        float bv = bias ? bias[o] : 0.f;
        #pragma unroll
        for (int j = 0; j < 4; j++)
            ob[(size_t)o * NPOS + pT + tx * 4 + j] = f2b(acc[i][j] + bv);
    }
}

// ---------------- K3: q softmax over d (in place, then *scale) ----------
__global__ __launch_bounds__(256) void q_softmax_kernel(bf16* __restrict__ qkv)
{
    int n = blockIdx.x * 256 + threadIdx.x;
    int m = blockIdx.y, b = blockIdx.z;
    bf16* q = qkv + ((size_t)b * OQKV + m * DHEAD) * NPOS + n;
    float r[DHEAD];
    float mx = -1e30f;
    #pragma unroll
    for (int i = 0; i < DHEAD; i++) { r[i] = b2f(q[(size_t)i * NPOS]); mx = fmaxf(mx, r[i]); }
    float s = 0.f;
    #pragma unroll
    for (int i = 0; i < DHEAD; i++) { r[i] = expf(r[i] - mx); s += r[i]; }
    float inv = QSCALE / s;
    #pragma unroll
    for (int i = 0; i < DHEAD; i++) q[(size_t)i * NPOS] = f2b(r[i] * inv);
}

// ---------------- K4: k softmax over n (in place) -----------------------
__global__ __launch_bounds__(256) void k_softmax_kernel(bf16* __restrict__ qkv)
{
    int d = blockIdx.x, m = blockIdx.y, b = blockIdx.z;
    bf16* row = qkv + ((size_t)b * OQKV + CH + m * DHEAD + d) * NPOS;
    __shared__ float red[256];
    int tid = threadIdx.x;
    float mx = -1e30f;
    for (int i = tid; i < NPOS; i += 256) mx = fmaxf(mx, b2f(row[i]));
    red[tid] = mx; __syncthreads();
    for (int s = 128; s > 0; s >>= 1) { if (tid < s) red[tid] = fmaxf(red[tid], red[tid + s]); __syncthreads(); }
    mx = red[0]; __syncthreads();
    float sum = 0.f;
    for (int i = tid; i < NPOS; i += 256) sum += expf(b2f(row[i]) - mx);
    red[tid] = sum; __syncthreads();
    for (int s = 128; s > 0; s >>= 1) { if (tid < s) red[tid] += red[tid + s]; __syncthreads(); }
    float inv = 1.f / red[0];
    for (int i = tid; i < NPOS; i += 256) row[i] = f2b(expf(b2f(row[i]) - mx) * inv);
}

// ---------------- K5: context partials ctx[i][j] = sum_n k[i,n]*v[j,n] ---
// 4-way split over n; partial s stored at ctx + (s*128 + b*8+m)*4096
__global__ __launch_bounds__(256) void ctx_gemm_kernel(
    const bf16* __restrict__ qkv, float* __restrict__ ctx)
{
    __shared__ float kt[32][65];   // [n][i]
    __shared__ float vt[32][65];   // [n][j]
    int tid = threadIdx.x;
    int tx = tid & 15, ty = tid >> 4;
    int split = blockIdx.x;
    int m = blockIdx.y, b = blockIdx.z;
    int nBase = split * (NPOS / 4);
    const bf16* kb = qkv + ((size_t)b * OQKV + CH     + m * DHEAD) * NPOS;
    const bf16* vb = qkv + ((size_t)b * OQKV + 2 * CH + m * DHEAD) * NPOS;
    float acc[4][4] = {};
    for (int nT = nBase; nT < nBase + NPOS / 4; nT += 32) {
        for (int l = tid; l < 64 * 32; l += 256) {
            int r = l >> 5, cc = l & 31;          // r: d-row, cc: n-col
            kt[cc][r] = b2f(kb[(size_t)r * NPOS + nT + cc]);
            vt[cc][r] = b2f(vb[(size_t)r * NPOS + nT + cc]);
        }
        __syncthreads();
        #pragma unroll
        for (int kk = 0; kk < 32; kk++) {
            float a[4], bb[4];
            #pragma unroll
            for (int i = 0; i < 4; i++) a[i]  = kt[kk][ty * 4 + i];
            #pragma unroll
            for (int j = 0; j < 4; j++) bb[j] = vt[kk][tx * 4 + j];
            #pragma unroll
            for (int i = 0; i < 4; i++)
                #pragma unroll
                for (int j = 0; j < 4; j++) acc[i][j] += a[i] * bb[j];
        }
        __syncthreads();
    }
    float* cb = ctx + ((size_t)split * BATCH * NHEAD + b * NHEAD + m) * (DHEAD * DHEAD);
    #pragma unroll
    for (int i = 0; i < 4; i++)
        #pragma unroll
        for (int j = 0; j < 4; j++)
            cb[(ty * 4 + i) * DHEAD + tx * 4 + j] = acc[i][j];
}

// ---------------- K6: out[j,n] = sum_i ctx[i,j] * q[i,n] → v-slot --------
__global__ __launch_bounds__(256) void attn_out_kernel(
    bf16* __restrict__ qkv, const float* __restrict__ ctx)
{
    __shared__ float sc[DHEAD * DHEAD];
    int tid = threadIdx.x;
    int nT = blockIdx.x * 256;
    int m = blockIdx.y, b = blockIdx.z;
    size_t cbase = (size_t)(b * NHEAD + m) * (DHEAD * DHEAD);
    for (int l = tid; l < DHEAD * DHEAD; l += 256) {
        float v = 0.f;
        #pragma unroll
        for (int s = 0; s < 4; s++)
            v += ctx[(size_t)s * BATCH * NHEAD * DHEAD * DHEAD + cbase + l];
        sc[l] = v;
    }
    __syncthreads();
    int n = nT + tid;
    const bf16* q = qkv + ((size_t)b * OQKV + m * DHEAD) * NPOS + n;
    float qr[DHEAD];
    #pragma unroll
    for (int i = 0; i < DHEAD; i++) qr[i] = b2f(q[(size_t)i * NPOS]);
    bf16* ov = qkv + ((size_t)b * OQKV + 2 * CH + m * DHEAD) * NPOS + n;
    for (int j = 0; j < DHEAD; j++) {
        float a = 0.f;
        #pragma unroll
        for (int i = 0; i < DHEAD; i++) a += sc[i * DHEAD + j] * qr[i];
        ov[(size_t)j * NPOS] = f2b(a);
    }
}

// ---------------- K8: final channel-LN, k-slot (bf16) → d_out (fp32) -----
__global__ __launch_bounds__(256) void ln_final_kernel(
    const bf16* __restrict__ qkv, const float* __restrict__ g2, float* __restrict__ out)
{
    int g = blockIdx.x * 256 + threadIdx.x;
    int b = g >> 12, p = g & 4095;
    const bf16* xp = qkv + ((size_t)b * OQKV + CH) * NPOS + p;
    float s = 0.f, s2 = 0.f;
    for (int c = 0; c < CH; c++) {
        float v = b2f(xp[(size_t)c * NPOS]);
        s += v; s2 += v * v;
    }
    float m = s * (1.f / CH);
    float var = s2 * (1.f / CH) - m * m;
    float rs = rsqrtf(var + EPSF);
    float* op = out + (size_t)b * CH * NPOS + p;
    for (int c = 0; c < CH; c++) {
        float v = b2f(xp[(size_t)c * NPOS]);
        op[(size_t)c * NPOS] = (v - m) * rs * g2[c];
    }
}

extern "C" void kernel_launch(void* const* d_in, const int* in_sizes, int n_in,
                              void* d_out, int out_size, void* d_ws, size_t ws_size,
                              hipStream_t stream)
{
    const float* x          = (const float*)d_in[0];
    const float* norm_g     = (const float*)d_in[1];
    const float* qkv_w      = (const float*)d_in[2];
    const float* out_w      = (const float*)d_in[3];
    const float* out_b      = (const float*)d_in[4];
    const float* out_norm_g = (const float*)d_in[5];
    float* outp = (float*)d_out;

    char* ws = (char*)d_ws;
    bf16*  qkv   = (bf16*)ws;                               // 16*1536*4096*2 = 201,326,592 B
    float* mean1 = (float*)(ws + (size_t)201326592);        // 65536 f32
    float* rstd1 = mean1 + 65536;                           // 65536 f32
    float* ctx   = rstd1 + 65536;                           // 4*16*8*64*64 f32 = 8 MB

    // 1. LN1 stats
    ln_stats_kernel<<<dim3(256), 256, 0, stream>>>(x, mean1, rstd1);
    // 2. QKV projection with fused LN on the fly (fp32 x -> bf16 qkv)
    gemm_chan_kernel<float><<<dim3(64, 24, 16), 256, 0, stream>>>(
        qkv_w, x, mean1, rstd1, norm_g, nullptr, qkv, CH, 0, OQKV, 0);
    // 3. q softmax over d (in place, *scale)
    q_softmax_kernel<<<dim3(16, NHEAD, BATCH), 256, 0, stream>>>(qkv);
    // 4. k softmax over n (in place)
    k_softmax_kernel<<<dim3(DHEAD, NHEAD, BATCH), 256, 0, stream>>>(qkv);
    // 5. context partials (4-way n-split)
    ctx_gemm_kernel<<<dim3(4, NHEAD, BATCH), 256, 0, stream>>>(qkv, ctx);
    // 6. attention out (ctx^T @ q) → v-slot
    attn_out_kernel<<<dim3(16, NHEAD, BATCH), 256, 0, stream>>>(qkv, ctx);
    // 7. out projection + bias → k-slot (bf16 v-slot in, bf16 k-slot out)
    gemm_chan_kernel<bf16><<<dim3(64, 8, 16), 256, 0, stream>>>(
        out_w, qkv, nullptr, nullptr, nullptr, out_b, qkv, OQKV, 2 * CH, OQKV, CH);
    // 8. final LN → d_out (fp32)
    ln_final_kernel<<<dim3(256), 256, 0, stream>>>(qkv, out_norm_g, outp);
}

// Round 3
// 964.953 us; speedup vs baseline: 4.1790x; 4.1790x over previous
//
#include <hip/hip_runtime.h>
#include <hip/hip_bf16.h>
#include <cstddef>

typedef __hip_bfloat16 bf16;
typedef __attribute__((ext_vector_type(8))) short s16x8;
typedef __attribute__((ext_vector_type(4))) short s16x4;
typedef __attribute__((ext_vector_type(4))) float f32x4;

static constexpr int BATCH = 16;
static constexpr int CH    = 512;    // DIM
static constexpr int NPOS  = 4096;   // h*w
static constexpr int OQKV  = 1536;   // 3*HID
static constexpr int NHEAD = 8;
static constexpr int DHEAD = 64;
#define EPSF 1e-5f
#define QSCALE 0.125f

__device__ __forceinline__ float b2f(bf16 v){ return __bfloat162float(v); }
__device__ __forceinline__ bf16  f2b(float v){ return __float2bfloat16(v); }
__device__ __forceinline__ unsigned short f2bbits(float v){
    bf16 t = __float2bfloat16(v);
    return *reinterpret_cast<unsigned short*>(&t);
}

// ---------------- K0: fp32 -> bf16 convert (weights) ----------------------
__global__ __launch_bounds__(256) void cvt_kernel(
    const float* __restrict__ in, bf16* __restrict__ out, int n)
{
    int i = blockIdx.x * 256 + threadIdx.x;
    if (i < n) out[i] = f2b(in[i]);
}

// ---------------- K1: fused chan-LN + transpose: x[c][p] fp32 -> xt[p][c] bf16
__global__ __launch_bounds__(256) void ln_transpose_kernel(
    const float* __restrict__ x, const float* __restrict__ g, bf16* __restrict__ xt)
{
    __shared__ float red[8][64];
    __shared__ float mean_s[64], rstd_s[64];
    __shared__ unsigned short tile[64][66];   // [p][c], pad 66: 2-way-free LDS
    int tid = threadIdx.x;
    int pl = tid & 63, cg = tid >> 6;
    int p0 = blockIdx.x * 64;
    int b  = blockIdx.y;
    const float* xb = x + (size_t)b * CH * NPOS;
    float s = 0.f, s2 = 0.f;
    for (int c = cg * 128; c < cg * 128 + 128; c++) {
        float v = xb[(size_t)c * NPOS + p0 + pl];
        s += v; s2 += v * v;
    }
    red[cg][pl] = s; red[4 + cg][pl] = s2;
    __syncthreads();
    if (tid < 64) {
        float ts  = red[0][tid] + red[1][tid] + red[2][tid] + red[3][tid];
        float ts2 = red[4][tid] + red[5][tid] + red[6][tid] + red[7][tid];
        float m   = ts * (1.f / CH);
        float var = ts2 * (1.f / CH) - m * m;
        mean_s[tid] = m;
        rstd_s[tid] = rsqrtf(var + EPSF);
    }
    __syncthreads();
    for (int c0 = 0; c0 < CH; c0 += 64) {
        #pragma unroll
        for (int it = 0; it < 16; it++) {
            int cl = it * 4 + cg;
            float v = xb[(size_t)(c0 + cl) * NPOS + p0 + pl];
            tile[pl][cl] = f2bbits((v - mean_s[pl]) * rstd_s[pl] * g[c0 + cl]);
        }
        __syncthreads();
        #pragma unroll
        for (int it = 0; it < 8; it++) {
            int r  = it * 8 + (tid >> 5);
            int cp = tid & 31;
            unsigned v = *(const unsigned*)&tile[r][cp * 2];
            *(unsigned*)(xt + ((size_t)b * NPOS + p0 + r) * CH + c0 + cp * 2) = v;
        }
        __syncthreads();
    }
}

// ---------------- K2/K7: MFMA bf16 GEMM, both operands K-contiguous ------
// C[b][o][p] = sum_k A[o][k] * B[b][n=p][k]  (+bias[o]), K=512, tile 128x128
__global__ __launch_bounds__(256) void mfma_gemm_kernel(
    const bf16* __restrict__ A, const bf16* __restrict__ B, size_t Bbatch,
    bf16* __restrict__ C, size_t Cbatch, const float* __restrict__ bias)
{
    // chunk-major LDS: slot s (16B) holds row m = s&127, kchunk c = s>>7
    __shared__ alignas(16) short As[8192];
    __shared__ alignas(16) short Bs[8192];
    int tid  = threadIdx.x;
    int lane = tid & 63, w = tid >> 6;
    int wr = w >> 1, wc = w & 1;
    int pT = blockIdx.x * 128;
    int oT = blockIdx.y * 128;
    int b  = blockIdx.z;
    const bf16* Bb = B + (size_t)b * Bbatch;

    f32x4 acc[4][4];
    #pragma unroll
    for (int i = 0; i < 4; i++)
        #pragma unroll
        for (int j = 0; j < 4; j++) acc[i][j] = f32x4{0.f, 0.f, 0.f, 0.f};

    for (int kT = 0; kT < 512; kT += 64) {
        #pragma unroll
        for (int it = 0; it < 4; it++) {
            int s = it * 256 + tid;
            int m = s & 127, c = s >> 7;
            const bf16* ga = A  + (size_t)(oT + m) * 512 + kT + c * 8;
            const bf16* gb = Bb + (size_t)(pT + m) * 512 + kT + c * 8;
            int sbase = it * 256 + w * 64;   // wave-uniform
            __builtin_amdgcn_global_load_lds(
                (const __attribute__((address_space(1))) void*)ga,
                (__attribute__((address_space(3))) void*)(As + (size_t)sbase * 8), 16, 0, 0);
            __builtin_amdgcn_global_load_lds(
                (const __attribute__((address_space(1))) void*)gb,
                (__attribute__((address_space(3))) void*)(Bs + (size_t)sbase * 8), 16, 0, 0);
        }
        __syncthreads();
        const s16x8* Av = (const s16x8*)As;
        const s16x8* Bv = (const s16x8*)Bs;
        #pragma unroll
        for (int kk = 0; kk < 2; kk++) {
            int cbase = kk * 4 + (lane >> 4);
            s16x8 af[4], bfg[4];
            #pragma unroll
            for (int i = 0; i < 4; i++)
                af[i] = Av[cbase * 128 + wr * 64 + i * 16 + (lane & 15)];
            #pragma unroll
            for (int j = 0; j < 4; j++)
                bfg[j] = Bv[cbase * 128 + wc * 64 + j * 16 + (lane & 15)];
            #pragma unroll
            for (int i = 0; i < 4; i++)
                #pragma unroll
                for (int j = 0; j < 4; j++)
                    acc[i][j] = __builtin_amdgcn_mfma_f32_16x16x32_bf16(
                        af[i], bfg[j], acc[i][j], 0, 0, 0);
        }
        __syncthreads();
    }
    bf16* Cb = C + (size_t)b * Cbatch;
    #pragma unroll
    for (int i = 0; i < 4; i++) {
        #pragma unroll
        for (int r = 0; r < 4; r++) {
            int o = oT + wr * 64 + i * 16 + (lane >> 4) * 4 + r;
            float bv = bias ? bias[o] : 0.f;
            #pragma unroll
            for (int j = 0; j < 4; j++) {
                int p = pT + wc * 64 + j * 16 + (lane & 15);
                Cb[(size_t)o * NPOS + p] = f2b(acc[i][j][r] + bv);
            }
        }
    }
}

// ---------------- K3: q softmax over d (in place, then *scale) ----------
__global__ __launch_bounds__(256) void q_softmax_kernel(bf16* __restrict__ qkv)
{
    int n = blockIdx.x * 256 + threadIdx.x;
    int m = blockIdx.y, b = blockIdx.z;
    bf16* q = qkv + ((size_t)b * OQKV + m * DHEAD) * NPOS + n;
    float r[DHEAD];
    float mx = -1e30f;
    #pragma unroll
    for (int i = 0; i < DHEAD; i++) { r[i] = b2f(q[(size_t)i * NPOS]); mx = fmaxf(mx, r[i]); }
    float s = 0.f;
    #pragma unroll
    for (int i = 0; i < DHEAD; i++) { r[i] = expf(r[i] - mx); s += r[i]; }
    float inv = QSCALE / s;
    #pragma unroll
    for (int i = 0; i < DHEAD; i++) q[(size_t)i * NPOS] = f2b(r[i] * inv);
}

// ---------------- K4: k softmax over n (in place) -----------------------
__global__ __launch_bounds__(256) void k_softmax_kernel(bf16* __restrict__ qkv)
{
    int d = blockIdx.x, m = blockIdx.y, b = blockIdx.z;
    bf16* row = qkv + ((size_t)b * OQKV + CH + m * DHEAD + d) * NPOS;
    __shared__ float red[256];
    int tid = threadIdx.x;
    float mx = -1e30f;
    for (int i = tid; i < NPOS; i += 256) mx = fmaxf(mx, b2f(row[i]));
    red[tid] = mx; __syncthreads();
    for (int s = 128; s > 0; s >>= 1) { if (tid < s) red[tid] = fmaxf(red[tid], red[tid + s]); __syncthreads(); }
    mx = red[0]; __syncthreads();
    float sum = 0.f;
    for (int i = tid; i < NPOS; i += 256) sum += expf(b2f(row[i]) - mx);
    red[tid] = sum; __syncthreads();
    for (int s = 128; s > 0; s >>= 1) { if (tid < s) red[tid] += red[tid + s]; __syncthreads(); }
    float inv = 1.f / red[0];
    for (int i = tid; i < NPOS; i += 256) row[i] = f2b(expf(b2f(row[i]) - mx) * inv);
}

// ---------------- K5: context partials ctx[i][j] = sum_n k[i,n]*v[j,n] ---
__global__ __launch_bounds__(256) void ctx_gemm_kernel(
    const bf16* __restrict__ qkv, float* __restrict__ ctx)
{
    __shared__ float kt[32][65];
    __shared__ float vt[32][65];
    int tid = threadIdx.x;
    int tx = tid & 15, ty = tid >> 4;
    int split = blockIdx.x;
    int m = blockIdx.y, b = blockIdx.z;
    int nBase = split * (NPOS / 4);
    const bf16* kb = qkv + ((size_t)b * OQKV + CH     + m * DHEAD) * NPOS;
    const bf16* vb = qkv + ((size_t)b * OQKV + 2 * CH + m * DHEAD) * NPOS;
    float acc[4][4] = {};
    for (int nT = nBase; nT < nBase + NPOS / 4; nT += 32) {
        for (int l = tid; l < 64 * 32; l += 256) {
            int r = l >> 5, cc = l & 31;
            kt[cc][r] = b2f(kb[(size_t)r * NPOS + nT + cc]);
            vt[cc][r] = b2f(vb[(size_t)r * NPOS + nT + cc]);
        }
        __syncthreads();
        #pragma unroll
        for (int kk = 0; kk < 32; kk++) {
            float a[4], bb[4];
            #pragma unroll
            for (int i = 0; i < 4; i++) a[i]  = kt[kk][ty * 4 + i];
            #pragma unroll
            for (int j = 0; j < 4; j++) bb[j] = vt[kk][tx * 4 + j];
            #pragma unroll
            for (int i = 0; i < 4; i++)
                #pragma unroll
                for (int j = 0; j < 4; j++) acc[i][j] += a[i] * bb[j];
        }
        __syncthreads();
    }
    float* cb = ctx + ((size_t)split * BATCH * NHEAD + b * NHEAD + m) * (DHEAD * DHEAD);
    #pragma unroll
    for (int i = 0; i < 4; i++)
        #pragma unroll
        for (int j = 0; j < 4; j++)
            cb[(ty * 4 + i) * DHEAD + tx * 4 + j] = acc[i][j];
}

// ---------------- K6: out[j,n]=sum_i ctx[i,j] q[i,n] → v-slot TRANSPOSED [n][hid]
__global__ __launch_bounds__(256) void attn_out_kernel(
    bf16* __restrict__ qkv, const float* __restrict__ ctx)
{
    __shared__ float sc[DHEAD * DHEAD];
    int tid = threadIdx.x;
    int nT = blockIdx.x * 256;
    int m = blockIdx.y, b = blockIdx.z;
    size_t cbase = (size_t)(b * NHEAD + m) * (DHEAD * DHEAD);
    for (int l = tid; l < DHEAD * DHEAD; l += 256) {
        float v = 0.f;
        #pragma unroll
        for (int s = 0; s < 4; s++)
            v += ctx[(size_t)s * BATCH * NHEAD * DHEAD * DHEAD + cbase + l];
        sc[l] = v;
    }
    __syncthreads();
    int n = nT + tid;
    const bf16* q = qkv + ((size_t)b * OQKV + m * DHEAD) * NPOS + n;
    float qr[DHEAD];
    #pragma unroll
    for (int i = 0; i < DHEAD; i++) qr[i] = b2f(q[(size_t)i * NPOS]);
    bf16* ovt = qkv + ((size_t)b * OQKV + 2 * CH) * NPOS + (size_t)n * (CH) + m * DHEAD;
    for (int jb = 0; jb < 16; jb++) {
        s16x4 pack;
        #pragma unroll
        for (int u = 0; u < 4; u++) {
            int j = jb * 4 + u;
            float a = 0.f;
            #pragma unroll
            for (int i = 0; i < DHEAD; i++) a += sc[i * DHEAD + j] * qr[i];
            pack[u] = (short)f2bbits(a);
        }
        *(s16x4*)(ovt + jb * 4) = pack;
    }
}

// ---------------- K8: final channel-LN, k-slot (bf16) → d_out (fp32) -----
__global__ __launch_bounds__(256) void ln_final_kernel(
    const bf16* __restrict__ qkv, const float* __restrict__ g2, float* __restrict__ out)
{
    int g = blockIdx.x * 256 + threadIdx.x;
    int b = g >> 12, p = g & 4095;
    const bf16* xp = qkv + ((size_t)b * OQKV + CH) * NPOS + p;
    float s = 0.f, s2 = 0.f;
    for (int c = 0; c < CH; c++) {
        float v = b2f(xp[(size_t)c * NPOS]);
        s += v; s2 += v * v;
    }
    float m = s * (1.f / CH);
    float var = s2 * (1.f / CH) - m * m;
    float rs = rsqrtf(var + EPSF);
    float* op = out + (size_t)b * CH * NPOS + p;
    for (int c = 0; c < CH; c++) {
        float v = b2f(xp[(size_t)c * NPOS]);
        op[(size_t)c * NPOS] = (v - m) * rs * g2[c];
    }
}

extern "C" void kernel_launch(void* const* d_in, const int* in_sizes, int n_in,
                              void* d_out, int out_size, void* d_ws, size_t ws_size,
                              hipStream_t stream)
{
    const float* x          = (const float*)d_in[0];
    const float* norm_g     = (const float*)d_in[1];
    const float* qkv_w      = (const float*)d_in[2];
    const float* out_w      = (const float*)d_in[3];
    const float* out_b      = (const float*)d_in[4];
    const float* out_norm_g = (const float*)d_in[5];
    float* outp = (float*)d_out;

    char* ws = (char*)d_ws;
    bf16*  qkv = (bf16*)ws;                                  // 201,326,592 B
    bf16*  wqb = (bf16*)(ws + (size_t)201326592);            // 1536*512 bf16
    bf16*  wob = wqb + (size_t)OQKV * CH;                    // 512*512 bf16
    float* ctx = (float*)(wob + (size_t)CH * CH);            // 4*16*8*64*64 f32
    bf16*  xnt = (bf16*)d_out;                               // xn^T [b][p][c] bf16, 64 MB (scratch until final LN)

    // 0. weight conversion
    cvt_kernel<<<dim3((OQKV * CH + 255) / 256), 256, 0, stream>>>(qkv_w, wqb, OQKV * CH);
    cvt_kernel<<<dim3((CH * CH + 255) / 256), 256, 0, stream>>>(out_w, wob, CH * CH);
    // 1. LN + transpose -> xn^T (in d_out scratch)
    ln_transpose_kernel<<<dim3(NPOS / 64, BATCH), 256, 0, stream>>>(x, norm_g, xnt);
    // 2. QKV projection (MFMA): [1536 x 4096] per batch
    mfma_gemm_kernel<<<dim3(NPOS / 128, OQKV / 128, BATCH), 256, 0, stream>>>(
        wqb, xnt, (size_t)NPOS * CH, qkv, (size_t)OQKV * NPOS, nullptr);
    // 3. q softmax over d
    q_softmax_kernel<<<dim3(16, NHEAD, BATCH), 256, 0, stream>>>(qkv);
    // 4. k softmax over n
    k_softmax_kernel<<<dim3(DHEAD, NHEAD, BATCH), 256, 0, stream>>>(qkv);
    // 5. context partials
    ctx_gemm_kernel<<<dim3(4, NHEAD, BATCH), 256, 0, stream>>>(qkv, ctx);
    // 6. attention out -> v-slot transposed [n][hid]
    attn_out_kernel<<<dim3(16, NHEAD, BATCH), 256, 0, stream>>>(qkv, ctx);
    // 7. out projection + bias (MFMA): [512 x 4096] per batch -> k-slot [o][p]
    mfma_gemm_kernel<<<dim3(NPOS / 128, CH / 128, BATCH), 256, 0, stream>>>(
        wob, qkv + (size_t)2 * CH * NPOS, (size_t)OQKV * NPOS,
        qkv + (size_t)CH * NPOS, (size_t)OQKV * NPOS, out_b);
    // 8. final LN -> d_out (overwrites xnt scratch; xnt dead by now)
    ln_final_kernel<<<dim3(256), 256, 0, stream>>>(qkv, out_norm_g, outp);
}